// Round 5
// baseline (914.104 us; speedup 1.0000x reference)
//
#include <hip/hip_runtime.h>

#define NSMP  8192
#define NDIM  3072
#define NK    64
#define NS    48
#define MK    200   // knots per transform
#define GB    256   // lookup-grid buckets

__device__ __forceinline__ float rcp_fast(float x) { return __builtin_amdgcn_rcpf(x); }
__device__ __forceinline__ int imin(int a, int b) { return a < b ? a : b; }

// ---------------------------------------------------------------------------
// Kernel 1: 64 independent 48x48 QR factorizations (modified Gram-Schmidt).
// Writes Q twice: row-major Qws[k][r][j] (phase C) and slice-packed
// Qpack[k][slice][r][jj] = Q[r][slice*12+jj] (phase A, contiguous 12/row).
// ---------------------------------------------------------------------------
__global__ __launch_bounds__(64) void qr_kernel(const float* __restrict__ Araw,
                                                float* __restrict__ Qws,
                                                float* __restrict__ Qpack) {
  const int k = blockIdx.x;
  const int lane = threadIdx.x;
  const float* Ak = Araw + k * NS * NS;
  float col[NS];
#pragma unroll
  for (int r = 0; r < NS; ++r)
    col[r] = (lane < NS) ? Ak[r * NS + lane] : 0.f;

  for (int j = 0; j < NS; ++j) {
    float q[NS];
#pragma unroll
    for (int r = 0; r < NS; ++r)
      q[r] = __int_as_float(__builtin_amdgcn_readlane(__float_as_int(col[r]), j));
    float n0 = 0.f, n1 = 0.f, n2 = 0.f, n3 = 0.f;
#pragma unroll
    for (int r = 0; r < NS; r += 4) {
      n0 = fmaf(q[r+0], q[r+0], n0); n1 = fmaf(q[r+1], q[r+1], n1);
      n2 = fmaf(q[r+2], q[r+2], n2); n3 = fmaf(q[r+3], q[r+3], n3);
    }
    float rinv = 1.0f / sqrtf((n0 + n1) + (n2 + n3));
#pragma unroll
    for (int r = 0; r < NS; ++r) q[r] *= rinv;
    if (lane == j) {
#pragma unroll
      for (int r = 0; r < NS; ++r) col[r] = q[r];
    } else if (lane > j && lane < NS) {
      float d0 = 0.f, d1 = 0.f, d2 = 0.f, d3 = 0.f;
#pragma unroll
      for (int r = 0; r < NS; r += 4) {
        d0 = fmaf(q[r+0], col[r+0], d0); d1 = fmaf(q[r+1], col[r+1], d1);
        d2 = fmaf(q[r+2], col[r+2], d2); d3 = fmaf(q[r+3], col[r+3], d3);
      }
      float dt = (d0 + d1) + (d2 + d3);
#pragma unroll
      for (int r = 0; r < NS; ++r) col[r] = fmaf(-dt, q[r], col[r]);
    }
  }
  if (lane < NS) {
    float* Qk = Qws + k * NS * NS;
    float* Pk = Qpack + k * NS * NS + (lane / 12) * (NS * 12) + (lane % 12);
#pragma unroll
    for (int r = 0; r < NS; ++r) {
      Qk[r * NS + lane] = col[r];
      Pk[r * 12] = col[r];
    }
  }
}

// ---------------------------------------------------------------------------
// Kernel 2: knot tables. One wave per transform row t.
//  xxg[t][0..199]    knot x positions
//  ydk8[t][kk]       2x float4: (xK, 1/dx, yK, dy), (s, dK, dK1, dK+dK1-2s)
//  edge[t*2+{0,1}]   (xx0,yy0,del0,scale), (xxM,yyM,delM,0)
//  gridb[t][g] u8    start interval for bucket g
// ---------------------------------------------------------------------------
__global__ __launch_bounds__(256) void knots_kernel(
    const float* __restrict__ x0, const float* __restrict__ logdx,
    const float* __restrict__ y0, const float* __restrict__ logdy,
    const float* __restrict__ logderiv,
    float* __restrict__ xxg, float4* __restrict__ ydk8,
    float4* __restrict__ edge, unsigned char* __restrict__ gridb) {
  const int wid = threadIdx.x >> 6, lane = threadIdx.x & 63;
  const int t = blockIdx.x * 4 + wid;
  __shared__ float sxx[4][MK], syy[4][MK], sdel[4][MK];

  {
    const float* row = logdx + t * (MK - 1);
    int i0 = lane * 4;
    float e0 = (i0 + 0 < MK - 1) ? __expf(row[i0 + 0]) : 0.f;
    float e1 = (i0 + 1 < MK - 1) ? __expf(row[i0 + 1]) : 0.f;
    float e2 = (i0 + 2 < MK - 1) ? __expf(row[i0 + 2]) : 0.f;
    float e3 = (i0 + 3 < MK - 1) ? __expf(row[i0 + 3]) : 0.f;
    float p0 = e0, p1 = p0 + e1, p2 = p1 + e2, p3 = p2 + e3;
    float incl = p3;
#pragma unroll
    for (int off = 1; off < 64; off <<= 1) {
      float u = __shfl_up(incl, off, 64);
      if (lane >= off) incl += u;
    }
    float xv = x0[t];
    float base = xv + (incl - p3);
    float* xrow = xxg + t * MK;
    if (lane == 0) { xrow[0] = xv; sxx[wid][0] = xv; }
    if (i0 + 0 < MK - 1) { xrow[1+i0+0] = base + p0; sxx[wid][1+i0+0] = base + p0; }
    if (i0 + 1 < MK - 1) { xrow[1+i0+1] = base + p1; sxx[wid][1+i0+1] = base + p1; }
    if (i0 + 2 < MK - 1) { xrow[1+i0+2] = base + p2; sxx[wid][1+i0+2] = base + p2; }
    if (i0 + 3 < MK - 1) { xrow[1+i0+3] = base + p3; sxx[wid][1+i0+3] = base + p3; }
  }
  {
    const float* row = logdy + t * (MK - 1);
    int i0 = lane * 4;
    float e0 = (i0 + 0 < MK - 1) ? __expf(row[i0 + 0]) : 0.f;
    float e1 = (i0 + 1 < MK - 1) ? __expf(row[i0 + 1]) : 0.f;
    float e2 = (i0 + 2 < MK - 1) ? __expf(row[i0 + 2]) : 0.f;
    float e3 = (i0 + 3 < MK - 1) ? __expf(row[i0 + 3]) : 0.f;
    float p0 = e0, p1 = p0 + e1, p2 = p1 + e2, p3 = p2 + e3;
    float incl = p3;
#pragma unroll
    for (int off = 1; off < 64; off <<= 1) {
      float u = __shfl_up(incl, off, 64);
      if (lane >= off) incl += u;
    }
    float yv = y0[t];
    float base = yv + (incl - p3);
    if (lane == 0) syy[wid][0] = yv;
    if (i0 + 0 < MK - 1) syy[wid][1+i0+0] = base + p0;
    if (i0 + 1 < MK - 1) syy[wid][1+i0+1] = base + p1;
    if (i0 + 2 < MK - 1) syy[wid][1+i0+2] = base + p2;
    if (i0 + 3 < MK - 1) syy[wid][1+i0+3] = base + p3;
  }
  {
    const float* ld = logderiv + t * MK;
#pragma unroll
    for (int rep = 0; rep < 4; ++rep) {
      int m = lane + rep * 64;
      if (m < MK) sdel[wid][m] = __expf(ld[m]);
    }
  }
  __syncthreads();

#pragma unroll
  for (int rep = 0; rep < 4; ++rep) {
    int kk = lane + rep * 64;
    if (kk < MK - 1) {
      float xK = sxx[wid][kk], dx = sxx[wid][kk+1] - xK;
      float yK = syy[wid][kk], dy = syy[wid][kk+1] - yK;
      float rdx = 1.0f / dx;
      float s_ = dy * rdx;
      float dK = sdel[wid][kk], dK1 = sdel[wid][kk+1];
      ydk8[(t * (MK-1) + kk) * 2 + 0] = make_float4(xK, rdx, yK, dy);
      ydk8[(t * (MK-1) + kk) * 2 + 1] = make_float4(s_, dK, dK1, dK + dK1 - 2.f * s_);
    }
  }
  float xx0v = sxx[wid][0], xxMv = sxx[wid][MK-1];
  if (lane == 0) {
    float scale = (float)GB / (xxMv - xx0v);
    edge[t*2+0] = make_float4(xx0v, syy[wid][0],    sdel[wid][0],    scale);
    edge[t*2+1] = make_float4(xxMv, syy[wid][MK-1], sdel[wid][MK-1], 0.f);
  }
  float bw = (xxMv - xx0v) * (1.f / (float)GB);
#pragma unroll
  for (int i = 0; i < 4; ++i) {
    int g = lane * 4 + i;
    float L = xx0v + (float)g * bw;
    int p = 0;
#pragma unroll
    for (int st = 128; st >= 1; st >>= 1) {
      int cand = p + st;
      if (cand < MK && sxx[wid][cand] < L) p = cand;
    }
    gridb[t * GB + g] = (unsigned char)(p > MK-2 ? MK-2 : p);
  }
}

// ---------------------------------------------------------------------------
// Fused core, SMALL-BLOCK variant (round 5): block = 256 thr = 4 waves,
// slice == wave-id (wave-uniform -> Q loads stay scalar-friendly), 64
// samples/block. Rationale: round 4 showed Occupancy 45% / VALUBusy 47% /
// HBM 12% with 8-wave barrier groups -- stall-bound, all waves coupled.
// Halving the group doubles independent barrier groups per CU (8 blocks x
// 13.8 KB LDS), occupancy cap 32 waves at 64 VGPR (launch_bounds(256,8)).
// nh-grouped decode kept: XCD x sees nh==x -> 2.9 MB tables L2-resident,
// nw-siblings adjacent for line assembly (round-4 fix, FETCH 535->154 MB).
// xs stride 50 keeps float2 ops 8B-aligned, banks <=2-way/broadcast.
// ---------------------------------------------------------------------------
__global__ __launch_bounds__(256, 8) void core_fused(
    const float* __restrict__ data, const float* __restrict__ Qws,
    const float* __restrict__ Qpack, const float* __restrict__ xxg,
    const unsigned char* __restrict__ gridb, const float4* __restrict__ edge,
    const float4* __restrict__ ydk8, float* __restrict__ partial,
    float* __restrict__ out) {
  const int w = blockIdx.x;
  const int nh = w & 7, nw = (w >> 3) & 7, tile = w >> 6;   // nh-grouped decode
  const int k = nh * 8 + nw;
  const int n0 = tile * 64;
  const int tid = threadIdx.x;
  const int srel = tid & 63;                                    // sample 0..63
  const int slice = __builtin_amdgcn_readfirstlane(tid >> 6);   // 0..3 == kh

  __shared__ float xs[64][50];    // x, then reused for e (stride 50: 8B align)
  __shared__ float lp[4][64];     // per-slice logsum partials

  const int r_img = (4 * nh + slice + 2) & 31;   // circular shift rows
  const int c0 = 12 * nw + 6;                    // circular shift cols (wraps)

  // ---- stage: read own 12-float chunk (sample srel, patch-row slice) ----
  float xreg[12];
  {
    const float* drow = data + (size_t)(n0 + srel) * NDIM + r_img * 96;
#pragma unroll
    for (int e = 0; e < 6; ++e) {
      int col = c0 + 2 * e; col -= (col >= 96) ? 96 : 0;
      float2 v = *(const float2*)(drow + col);
      xreg[2*e] = v.x; xreg[2*e+1] = v.y;
      *(float2*)&xs[srel][slice * 12 + 2*e] = v;
    }
  }
  __syncthreads();

  // ---- phase A: acc[12] = x . Q[:, slice*12 .. +11]  (Qpack contiguous) ----
  float acc[12];
#pragma unroll
  for (int j = 0; j < 12; ++j) acc[j] = 0.f;
  {
    const float4* qa = (const float4*)(Qpack + k * NS * NS + slice * (NS * 12));
#pragma unroll 4
    for (int d2 = 0; d2 < 24; ++d2) {              // d = 2*d2, 2*d2+1
      float2 xv = *(const float2*)&xs[srel][2 * d2];
      float4 a0 = qa[(2*d2)*3+0], a1 = qa[(2*d2)*3+1], a2 = qa[(2*d2)*3+2];
      float4 b0 = qa[(2*d2)*3+3], b1 = qa[(2*d2)*3+4], b2 = qa[(2*d2)*3+5];
      acc[0] = fmaf(xv.x, a0.x, acc[0]); acc[1] = fmaf(xv.x, a0.y, acc[1]);
      acc[2] = fmaf(xv.x, a0.z, acc[2]); acc[3] = fmaf(xv.x, a0.w, acc[3]);
      acc[4] = fmaf(xv.x, a1.x, acc[4]); acc[5] = fmaf(xv.x, a1.y, acc[5]);
      acc[6] = fmaf(xv.x, a1.z, acc[6]); acc[7] = fmaf(xv.x, a1.w, acc[7]);
      acc[8] = fmaf(xv.x, a2.x, acc[8]); acc[9] = fmaf(xv.x, a2.y, acc[9]);
      acc[10]= fmaf(xv.x, a2.z, acc[10]); acc[11]= fmaf(xv.x, a2.w, acc[11]);
      acc[0] = fmaf(xv.y, b0.x, acc[0]); acc[1] = fmaf(xv.y, b0.y, acc[1]);
      acc[2] = fmaf(xv.y, b0.z, acc[2]); acc[3] = fmaf(xv.y, b0.w, acc[3]);
      acc[4] = fmaf(xv.y, b1.x, acc[4]); acc[5] = fmaf(xv.y, b1.y, acc[5]);
      acc[6] = fmaf(xv.y, b1.z, acc[6]); acc[7] = fmaf(xv.y, b1.w, acc[7]);
      acc[8] = fmaf(xv.y, b2.x, acc[8]); acc[9] = fmaf(xv.y, b2.y, acc[9]);
      acc[10]= fmaf(xv.y, b2.z, acc[10]); acc[11]= fmaf(xv.y, b2.w, acc[11]);
    }
  }

  // ---- phase B: spline on 12 values, e = y - d0 (registers only) ----
  // log-sum as product-of-12 then one log: dd ~ O(1), product in fp32 range.
  float prod = 1.f;
  {
    const unsigned char* gk = gridb + (size_t)k * NS * GB;
    const float4* yk = ydk8 + (size_t)k * NS * (MK - 1) * 2;
    const float4* ek = edge + (size_t)k * NS * 2;
    const float* xk = xxg + (size_t)k * NS * MK;
#pragma unroll
    for (int jj = 0; jj < 12; ++jj) {
      const int jg = slice * 12 + jj;
      float v = acc[jj];
      float4 e0 = ek[2*jg], e1 = ek[2*jg+1];
      int g = (int)((v - e0.x) * e0.w);
      g = g < 0 ? 0 : (g > GB-1 ? GB-1 : g);
      int kk = gk[jg * GB + g];
      const float* xr = xk + jg * MK;
      // parallel refine: monotone xx => independent compares sum correctly
      float xA = xr[imin(kk + 1, MK - 1)];
      float xB = xr[imin(kk + 2, MK - 1)];
      float xC = xr[imin(kk + 3, MK - 1)];
      kk += (int)(kk + 1 <= MK-2 && xA < v) + (int)(kk + 2 <= MK-2 && xB < v)
          + (int)(kk + 3 <= MK-2 && xC < v);
      float4 r0 = yk[(jg * (MK-1) + kk) * 2 + 0];   // (xK, rdx, yK, dy)
      float4 r1 = yk[(jg * (MK-1) + kk) * 2 + 1];   // (s, dK, dK1, d2s)
      float xi = (v - r0.x) * r0.y;
      xi = fminf(fmaxf(xi, 0.f), 1.f);
      float omxi = 1.f - xi, xi1 = xi * omxi, xi2 = xi * xi;
      float denom = fmaf(r1.w, xi1, r1.x);
      float rden = rcp_fast(denom);
      float y_in = fmaf(r0.w * fmaf(r1.x, xi2, r1.y * xi1), rden, r0.z);
      float d_in = r1.x * r1.x * (r1.z * xi2 + 2.f * r1.x * xi1 + r1.y * omxi * omxi) * (rden * rden);
      bool below = v <= e0.x, above = v > e1.x;
      float yv = below ? fmaf(e0.z, v - e0.x, e0.y)
               : (above ? fmaf(e1.z, v - e1.x, e1.y) : y_in);
      float dd = below ? e0.z : (above ? e1.z : d_in);
      prod *= dd;
      acc[jj] = yv - v;
    }
  }

  // ---- publish e into xs (reuse; x stays in xreg) + logsum partial ----
  __syncthreads();   // all phase-A reads of xs complete
#pragma unroll
  for (int jj = 0; jj < 12; jj += 2)
    *(float2*)&xs[srel][slice * 12 + jj] = make_float2(acc[jj], acc[jj+1]);
  lp[slice][srel] = __logf(prod);
  __syncthreads();

  // ---- phase C: r[dd] = e . Q[slice*12+dd][:]  (j-chunks of 4, float4 Q) ----
  float r[12];
#pragma unroll
  for (int d = 0; d < 12; ++d) r[d] = 0.f;
  {
    const float* qc = Qws + k * NS * NS + (slice * 12) * NS;
#pragma unroll
    for (int jc = 0; jc < 12; ++jc) {
      float2 eab = *(const float2*)&xs[srel][4 * jc];
      float2 ecd = *(const float2*)&xs[srel][4 * jc + 2];
#pragma unroll
      for (int dd = 0; dd < 12; ++dd) {
        float4 q = *(const float4*)(qc + dd * NS + 4 * jc);
        r[dd] = fmaf(ecd.y, q.w, fmaf(ecd.x, q.z, fmaf(eab.y, q.y, fmaf(eab.x, q.x, r[dd]))));
      }
    }
  }

  // ---- epilogue: out = x + r, same chunk this thread loaded ----
  {
    float* orow = out + (size_t)(n0 + srel) * NDIM + r_img * 96;
#pragma unroll
    for (int e = 0; e < 6; ++e) {
      int col = c0 + 2 * e; col -= (col >= 96) ? 96 : 0;
      *(float2*)(orow + col) = make_float2(xreg[2*e] + r[2*e],
                                           xreg[2*e+1] + r[2*e+1]);
    }
  }

  // ---- logsum reduction across slices (global store last) ----
  if (tid < 64) {
    float t = lp[0][tid] + lp[1][tid] + lp[2][tid] + lp[3][tid];
    partial[(size_t)k * NSMP + n0 + tid] = t;
  }
}

__global__ __launch_bounds__(256) void reduce_kernel(const float* __restrict__ partial,
                                                     float* __restrict__ logj) {
  int n = blockIdx.x * 256 + threadIdx.x;
  float s = 0.f;
#pragma unroll
  for (int k = 0; k < NK; ++k) s += partial[k * NSMP + n];
  logj[n] = s;
}

extern "C" void kernel_launch(void* const* d_in, const int* in_sizes, int n_in,
                              void* d_out, int out_size, void* d_ws, size_t ws_size,
                              hipStream_t stream) {
  const float* data     = (const float*)d_in[0];
  const float* Araw     = (const float*)d_in[1];
  const float* x0       = (const float*)d_in[2];
  const float* logdx    = (const float*)d_in[3];
  const float* y0       = (const float*)d_in[4];
  const float* logdy    = (const float*)d_in[5];
  const float* logderiv = (const float*)d_in[6];
  float* out = (float*)d_out;
  float* ws  = (float*)d_ws;

  float*         Qws   = ws;                                 // 589,824 B
  float*         Qpack = Qws + 64 * NS * NS;                 // 589,824 B
  float*         xxg   = Qpack + 64 * NS * NS;               // 2,457,600 B
  float4*        ydk8  = (float4*)(xxg + 3072 * MK);         // 19,562,496 B
  float4*        edge  = ydk8 + 3072 * (MK - 1) * 2;         // 98,304 B
  unsigned char* gridb = (unsigned char*)(edge + 3072 * 2);  // 786,432 B
  float*         partial = (float*)(gridb + 3072 * GB);      // 2,097,152 B

  qr_kernel<<<64, 64, 0, stream>>>(Araw, Qws, Qpack);
  knots_kernel<<<768, 256, 0, stream>>>(x0, logdx, y0, logdy, logderiv,
                                        xxg, ydk8, edge, gridb);
  core_fused<<<(NSMP / 64) * 64, 256, 0, stream>>>(data, Qws, Qpack, xxg,
                                                   gridb, edge, ydk8,
                                                   partial, out);
  reduce_kernel<<<32, 256, 0, stream>>>(partial, out + (size_t)NSMP * NDIM);
}

// Round 6
// 484.300 us; speedup vs baseline: 1.8875x; 1.8875x over previous
//
#include <hip/hip_runtime.h>

#define NSMP  8192
#define NDIM  3072
#define NK    64
#define NS    48
#define MK    200   // knots per transform
#define GB    256   // lookup-grid buckets

__device__ __forceinline__ float rcp_fast(float x) { return __builtin_amdgcn_rcpf(x); }
__device__ __forceinline__ int imin(int a, int b) { return a < b ? a : b; }

// ---------------------------------------------------------------------------
// Kernel 1: 64 independent 48x48 QR factorizations (modified Gram-Schmidt).
// Writes Q twice: row-major Qws[k][r][j] (phase C) and slice-packed
// Qpack[k][slice][r][jj] = Q[r][slice*12+jj] (phase A, contiguous 12/row).
// ---------------------------------------------------------------------------
__global__ __launch_bounds__(64) void qr_kernel(const float* __restrict__ Araw,
                                                float* __restrict__ Qws,
                                                float* __restrict__ Qpack) {
  const int k = blockIdx.x;
  const int lane = threadIdx.x;
  const float* Ak = Araw + k * NS * NS;
  float col[NS];
#pragma unroll
  for (int r = 0; r < NS; ++r)
    col[r] = (lane < NS) ? Ak[r * NS + lane] : 0.f;

  for (int j = 0; j < NS; ++j) {
    float q[NS];
#pragma unroll
    for (int r = 0; r < NS; ++r)
      q[r] = __int_as_float(__builtin_amdgcn_readlane(__float_as_int(col[r]), j));
    float n0 = 0.f, n1 = 0.f, n2 = 0.f, n3 = 0.f;
#pragma unroll
    for (int r = 0; r < NS; r += 4) {
      n0 = fmaf(q[r+0], q[r+0], n0); n1 = fmaf(q[r+1], q[r+1], n1);
      n2 = fmaf(q[r+2], q[r+2], n2); n3 = fmaf(q[r+3], q[r+3], n3);
    }
    float rinv = 1.0f / sqrtf((n0 + n1) + (n2 + n3));
#pragma unroll
    for (int r = 0; r < NS; ++r) q[r] *= rinv;
    if (lane == j) {
#pragma unroll
      for (int r = 0; r < NS; ++r) col[r] = q[r];
    } else if (lane > j && lane < NS) {
      float d0 = 0.f, d1 = 0.f, d2 = 0.f, d3 = 0.f;
#pragma unroll
      for (int r = 0; r < NS; r += 4) {
        d0 = fmaf(q[r+0], col[r+0], d0); d1 = fmaf(q[r+1], col[r+1], d1);
        d2 = fmaf(q[r+2], col[r+2], d2); d3 = fmaf(q[r+3], col[r+3], d3);
      }
      float dt = (d0 + d1) + (d2 + d3);
#pragma unroll
      for (int r = 0; r < NS; ++r) col[r] = fmaf(-dt, q[r], col[r]);
    }
  }
  if (lane < NS) {
    float* Qk = Qws + k * NS * NS;
    float* Pk = Qpack + k * NS * NS + (lane / 12) * (NS * 12) + (lane % 12);
#pragma unroll
    for (int r = 0; r < NS; ++r) {
      Qk[r * NS + lane] = col[r];
      Pk[r * 12] = col[r];
    }
  }
}

// ---------------------------------------------------------------------------
// Kernel 2: knot tables. One wave per transform row t.
//  xxg[t][0..199]    knot x positions
//  ydk8[t][kk]       2x float4: (xK, 1/dx, yK, dy), (s, dK, dK1, dK+dK1-2s)
//  edge[t*2+{0,1}]   (xx0,yy0,del0,scale), (xxM,yyM,delM,0)
//  gridb[t][g] u8    start interval for bucket g
// ---------------------------------------------------------------------------
__global__ __launch_bounds__(256) void knots_kernel(
    const float* __restrict__ x0, const float* __restrict__ logdx,
    const float* __restrict__ y0, const float* __restrict__ logdy,
    const float* __restrict__ logderiv,
    float* __restrict__ xxg, float4* __restrict__ ydk8,
    float4* __restrict__ edge, unsigned char* __restrict__ gridb) {
  const int wid = threadIdx.x >> 6, lane = threadIdx.x & 63;
  const int t = blockIdx.x * 4 + wid;
  __shared__ float sxx[4][MK], syy[4][MK], sdel[4][MK];

  {
    const float* row = logdx + t * (MK - 1);
    int i0 = lane * 4;
    float e0 = (i0 + 0 < MK - 1) ? __expf(row[i0 + 0]) : 0.f;
    float e1 = (i0 + 1 < MK - 1) ? __expf(row[i0 + 1]) : 0.f;
    float e2 = (i0 + 2 < MK - 1) ? __expf(row[i0 + 2]) : 0.f;
    float e3 = (i0 + 3 < MK - 1) ? __expf(row[i0 + 3]) : 0.f;
    float p0 = e0, p1 = p0 + e1, p2 = p1 + e2, p3 = p2 + e3;
    float incl = p3;
#pragma unroll
    for (int off = 1; off < 64; off <<= 1) {
      float u = __shfl_up(incl, off, 64);
      if (lane >= off) incl += u;
    }
    float xv = x0[t];
    float base = xv + (incl - p3);
    float* xrow = xxg + t * MK;
    if (lane == 0) { xrow[0] = xv; sxx[wid][0] = xv; }
    if (i0 + 0 < MK - 1) { xrow[1+i0+0] = base + p0; sxx[wid][1+i0+0] = base + p0; }
    if (i0 + 1 < MK - 1) { xrow[1+i0+1] = base + p1; sxx[wid][1+i0+1] = base + p1; }
    if (i0 + 2 < MK - 1) { xrow[1+i0+2] = base + p2; sxx[wid][1+i0+2] = base + p2; }
    if (i0 + 3 < MK - 1) { xrow[1+i0+3] = base + p3; sxx[wid][1+i0+3] = base + p3; }
  }
  {
    const float* row = logdy + t * (MK - 1);
    int i0 = lane * 4;
    float e0 = (i0 + 0 < MK - 1) ? __expf(row[i0 + 0]) : 0.f;
    float e1 = (i0 + 1 < MK - 1) ? __expf(row[i0 + 1]) : 0.f;
    float e2 = (i0 + 2 < MK - 1) ? __expf(row[i0 + 2]) : 0.f;
    float e3 = (i0 + 3 < MK - 1) ? __expf(row[i0 + 3]) : 0.f;
    float p0 = e0, p1 = p0 + e1, p2 = p1 + e2, p3 = p2 + e3;
    float incl = p3;
#pragma unroll
    for (int off = 1; off < 64; off <<= 1) {
      float u = __shfl_up(incl, off, 64);
      if (lane >= off) incl += u;
    }
    float yv = y0[t];
    float base = yv + (incl - p3);
    if (lane == 0) syy[wid][0] = yv;
    if (i0 + 0 < MK - 1) syy[wid][1+i0+0] = base + p0;
    if (i0 + 1 < MK - 1) syy[wid][1+i0+1] = base + p1;
    if (i0 + 2 < MK - 1) syy[wid][1+i0+2] = base + p2;
    if (i0 + 3 < MK - 1) syy[wid][1+i0+3] = base + p3;
  }
  {
    const float* ld = logderiv + t * MK;
#pragma unroll
    for (int rep = 0; rep < 4; ++rep) {
      int m = lane + rep * 64;
      if (m < MK) sdel[wid][m] = __expf(ld[m]);
    }
  }
  __syncthreads();

#pragma unroll
  for (int rep = 0; rep < 4; ++rep) {
    int kk = lane + rep * 64;
    if (kk < MK - 1) {
      float xK = sxx[wid][kk], dx = sxx[wid][kk+1] - xK;
      float yK = syy[wid][kk], dy = syy[wid][kk+1] - yK;
      float rdx = 1.0f / dx;
      float s_ = dy * rdx;
      float dK = sdel[wid][kk], dK1 = sdel[wid][kk+1];
      ydk8[(t * (MK-1) + kk) * 2 + 0] = make_float4(xK, rdx, yK, dy);
      ydk8[(t * (MK-1) + kk) * 2 + 1] = make_float4(s_, dK, dK1, dK + dK1 - 2.f * s_);
    }
  }
  float xx0v = sxx[wid][0], xxMv = sxx[wid][MK-1];
  if (lane == 0) {
    float scale = (float)GB / (xxMv - xx0v);
    edge[t*2+0] = make_float4(xx0v, syy[wid][0],    sdel[wid][0],    scale);
    edge[t*2+1] = make_float4(xxMv, syy[wid][MK-1], sdel[wid][MK-1], 0.f);
  }
  float bw = (xxMv - xx0v) * (1.f / (float)GB);
#pragma unroll
  for (int i = 0; i < 4; ++i) {
    int g = lane * 4 + i;
    float L = xx0v + (float)g * bw;
    int p = 0;
#pragma unroll
    for (int st = 128; st >= 1; st >>= 1) {
      int cand = p + st;
      if (cand < MK && sxx[wid][cand] < L) p = cand;
    }
    gridb[t * GB + g] = (unsigned char)(p > MK-2 ? MK-2 : p);
  }
}

// ---------------------------------------------------------------------------
// Fused core, small-block variant (round 6): block = 256 thr = 4 waves,
// slice == wave-id, 64 samples/block, nh-grouped XCD decode (round-4 fix).
//
// launch_bounds = (256, 4): round 5's (256, 8) capped the allocator at
// 64 VGPR (granularity -> 32) and spilled the ~45-float per-thread state
// to scratch (WRITE 1.25 GB, core 714 us) -- while proving the small-block
// occupancy gain (81%). With the 128-VGPR cap the round-4 body compiled to
// 64 VGPR; at 64 VGPR the HW still allows 8 waves/SIMD = 8 blocks/CU
// (LDS 13.8 KB x 8 = 110 KB < 160), so we keep the occupancy WITHOUT
// forcing the register squeeze.
// ---------------------------------------------------------------------------
__global__ __launch_bounds__(256, 4) void core_fused(
    const float* __restrict__ data, const float* __restrict__ Qws,
    const float* __restrict__ Qpack, const float* __restrict__ xxg,
    const unsigned char* __restrict__ gridb, const float4* __restrict__ edge,
    const float4* __restrict__ ydk8, float* __restrict__ partial,
    float* __restrict__ out) {
  const int w = blockIdx.x;
  const int nh = w & 7, nw = (w >> 3) & 7, tile = w >> 6;   // nh-grouped decode
  const int k = nh * 8 + nw;
  const int n0 = tile * 64;
  const int tid = threadIdx.x;
  const int srel = tid & 63;                                    // sample 0..63
  const int slice = __builtin_amdgcn_readfirstlane(tid >> 6);   // 0..3 == kh

  __shared__ float xs[64][50];    // x, then reused for e (stride 50: 8B align)
  __shared__ float lp[4][64];     // per-slice logsum partials

  const int r_img = (4 * nh + slice + 2) & 31;   // circular shift rows
  const int c0 = 12 * nw + 6;                    // circular shift cols (wraps)

  // ---- stage: read own 12-float chunk (sample srel, patch-row slice) ----
  float xreg[12];
  {
    const float* drow = data + (size_t)(n0 + srel) * NDIM + r_img * 96;
#pragma unroll
    for (int e = 0; e < 6; ++e) {
      int col = c0 + 2 * e; col -= (col >= 96) ? 96 : 0;
      float2 v = *(const float2*)(drow + col);
      xreg[2*e] = v.x; xreg[2*e+1] = v.y;
      *(float2*)&xs[srel][slice * 12 + 2*e] = v;
    }
  }
  __syncthreads();

  // ---- phase A: acc[12] = x . Q[:, slice*12 .. +11]  (Qpack contiguous) ----
  float acc[12];
#pragma unroll
  for (int j = 0; j < 12; ++j) acc[j] = 0.f;
  {
    const float4* qa = (const float4*)(Qpack + k * NS * NS + slice * (NS * 12));
#pragma unroll 4
    for (int d2 = 0; d2 < 24; ++d2) {              // d = 2*d2, 2*d2+1
      float2 xv = *(const float2*)&xs[srel][2 * d2];
      float4 a0 = qa[(2*d2)*3+0], a1 = qa[(2*d2)*3+1], a2 = qa[(2*d2)*3+2];
      float4 b0 = qa[(2*d2)*3+3], b1 = qa[(2*d2)*3+4], b2 = qa[(2*d2)*3+5];
      acc[0] = fmaf(xv.x, a0.x, acc[0]); acc[1] = fmaf(xv.x, a0.y, acc[1]);
      acc[2] = fmaf(xv.x, a0.z, acc[2]); acc[3] = fmaf(xv.x, a0.w, acc[3]);
      acc[4] = fmaf(xv.x, a1.x, acc[4]); acc[5] = fmaf(xv.x, a1.y, acc[5]);
      acc[6] = fmaf(xv.x, a1.z, acc[6]); acc[7] = fmaf(xv.x, a1.w, acc[7]);
      acc[8] = fmaf(xv.x, a2.x, acc[8]); acc[9] = fmaf(xv.x, a2.y, acc[9]);
      acc[10]= fmaf(xv.x, a2.z, acc[10]); acc[11]= fmaf(xv.x, a2.w, acc[11]);
      acc[0] = fmaf(xv.y, b0.x, acc[0]); acc[1] = fmaf(xv.y, b0.y, acc[1]);
      acc[2] = fmaf(xv.y, b0.z, acc[2]); acc[3] = fmaf(xv.y, b0.w, acc[3]);
      acc[4] = fmaf(xv.y, b1.x, acc[4]); acc[5] = fmaf(xv.y, b1.y, acc[5]);
      acc[6] = fmaf(xv.y, b1.z, acc[6]); acc[7] = fmaf(xv.y, b1.w, acc[7]);
      acc[8] = fmaf(xv.y, b2.x, acc[8]); acc[9] = fmaf(xv.y, b2.y, acc[9]);
      acc[10]= fmaf(xv.y, b2.z, acc[10]); acc[11]= fmaf(xv.y, b2.w, acc[11]);
    }
  }

  // ---- phase B: spline on 12 values, e = y - d0 (registers only) ----
  // log-sum as product-of-12 then one log: dd ~ O(1), product in fp32 range.
  float prod = 1.f;
  {
    const unsigned char* gk = gridb + (size_t)k * NS * GB;
    const float4* yk = ydk8 + (size_t)k * NS * (MK - 1) * 2;
    const float4* ek = edge + (size_t)k * NS * 2;
    const float* xk = xxg + (size_t)k * NS * MK;
#pragma unroll
    for (int jj = 0; jj < 12; ++jj) {
      const int jg = slice * 12 + jj;
      float v = acc[jj];
      float4 e0 = ek[2*jg], e1 = ek[2*jg+1];
      int g = (int)((v - e0.x) * e0.w);
      g = g < 0 ? 0 : (g > GB-1 ? GB-1 : g);
      int kk = gk[jg * GB + g];
      const float* xr = xk + jg * MK;
      // parallel refine: monotone xx => independent compares sum correctly
      float xA = xr[imin(kk + 1, MK - 1)];
      float xB = xr[imin(kk + 2, MK - 1)];
      float xC = xr[imin(kk + 3, MK - 1)];
      kk += (int)(kk + 1 <= MK-2 && xA < v) + (int)(kk + 2 <= MK-2 && xB < v)
          + (int)(kk + 3 <= MK-2 && xC < v);
      float4 r0 = yk[(jg * (MK-1) + kk) * 2 + 0];   // (xK, rdx, yK, dy)
      float4 r1 = yk[(jg * (MK-1) + kk) * 2 + 1];   // (s, dK, dK1, d2s)
      float xi = (v - r0.x) * r0.y;
      xi = fminf(fmaxf(xi, 0.f), 1.f);
      float omxi = 1.f - xi, xi1 = xi * omxi, xi2 = xi * xi;
      float denom = fmaf(r1.w, xi1, r1.x);
      float rden = rcp_fast(denom);
      float y_in = fmaf(r0.w * fmaf(r1.x, xi2, r1.y * xi1), rden, r0.z);
      float d_in = r1.x * r1.x * (r1.z * xi2 + 2.f * r1.x * xi1 + r1.y * omxi * omxi) * (rden * rden);
      bool below = v <= e0.x, above = v > e1.x;
      float yv = below ? fmaf(e0.z, v - e0.x, e0.y)
               : (above ? fmaf(e1.z, v - e1.x, e1.y) : y_in);
      float dd = below ? e0.z : (above ? e1.z : d_in);
      prod *= dd;
      acc[jj] = yv - v;
    }
  }

  // ---- publish e into xs (reuse; x stays in xreg) + logsum partial ----
  __syncthreads();   // all phase-A reads of xs complete
#pragma unroll
  for (int jj = 0; jj < 12; jj += 2)
    *(float2*)&xs[srel][slice * 12 + jj] = make_float2(acc[jj], acc[jj+1]);
  lp[slice][srel] = __logf(prod);
  __syncthreads();

  // ---- phase C: r[dd] = e . Q[slice*12+dd][:]  (j-chunks of 4, float4 Q) ----
  float r[12];
#pragma unroll
  for (int d = 0; d < 12; ++d) r[d] = 0.f;
  {
    const float* qc = Qws + k * NS * NS + (slice * 12) * NS;
#pragma unroll
    for (int jc = 0; jc < 12; ++jc) {
      float2 eab = *(const float2*)&xs[srel][4 * jc];
      float2 ecd = *(const float2*)&xs[srel][4 * jc + 2];
#pragma unroll
      for (int dd = 0; dd < 12; ++dd) {
        float4 q = *(const float4*)(qc + dd * NS + 4 * jc);
        r[dd] = fmaf(ecd.y, q.w, fmaf(ecd.x, q.z, fmaf(eab.y, q.y, fmaf(eab.x, q.x, r[dd]))));
      }
    }
  }

  // ---- epilogue: out = x + r, same chunk this thread loaded ----
  {
    float* orow = out + (size_t)(n0 + srel) * NDIM + r_img * 96;
#pragma unroll
    for (int e = 0; e < 6; ++e) {
      int col = c0 + 2 * e; col -= (col >= 96) ? 96 : 0;
      *(float2*)(orow + col) = make_float2(xreg[2*e] + r[2*e],
                                           xreg[2*e+1] + r[2*e+1]);
    }
  }

  // ---- logsum reduction across slices (global store last) ----
  if (tid < 64) {
    float t = lp[0][tid] + lp[1][tid] + lp[2][tid] + lp[3][tid];
    partial[(size_t)k * NSMP + n0 + tid] = t;
  }
}

__global__ __launch_bounds__(256) void reduce_kernel(const float* __restrict__ partial,
                                                     float* __restrict__ logj) {
  int n = blockIdx.x * 256 + threadIdx.x;
  float s = 0.f;
#pragma unroll
  for (int k = 0; k < NK; ++k) s += partial[k * NSMP + n];
  logj[n] = s;
}

extern "C" void kernel_launch(void* const* d_in, const int* in_sizes, int n_in,
                              void* d_out, int out_size, void* d_ws, size_t ws_size,
                              hipStream_t stream) {
  const float* data     = (const float*)d_in[0];
  const float* Araw     = (const float*)d_in[1];
  const float* x0       = (const float*)d_in[2];
  const float* logdx    = (const float*)d_in[3];
  const float* y0       = (const float*)d_in[4];
  const float* logdy    = (const float*)d_in[5];
  const float* logderiv = (const float*)d_in[6];
  float* out = (float*)d_out;
  float* ws  = (float*)d_ws;

  float*         Qws   = ws;                                 // 589,824 B
  float*         Qpack = Qws + 64 * NS * NS;                 // 589,824 B
  float*         xxg   = Qpack + 64 * NS * NS;               // 2,457,600 B
  float4*        ydk8  = (float4*)(xxg + 3072 * MK);         // 19,562,496 B
  float4*        edge  = ydk8 + 3072 * (MK - 1) * 2;         // 98,304 B
  unsigned char* gridb = (unsigned char*)(edge + 3072 * 2);  // 786,432 B
  float*         partial = (float*)(gridb + 3072 * GB);      // 2,097,152 B

  qr_kernel<<<64, 64, 0, stream>>>(Araw, Qws, Qpack);
  knots_kernel<<<768, 256, 0, stream>>>(x0, logdx, y0, logdy, logderiv,
                                        xxg, ydk8, edge, gridb);
  core_fused<<<(NSMP / 64) * 64, 256, 0, stream>>>(data, Qws, Qpack, xxg,
                                                   gridb, edge, ydk8,
                                                   partial, out);
  reduce_kernel<<<32, 256, 0, stream>>>(partial, out + (size_t)NSMP * NDIM);
}

// Round 7
// 465.517 us; speedup vs baseline: 1.9636x; 1.0404x over previous
//
#include <hip/hip_runtime.h>

#define NSMP  8192
#define NDIM  3072
#define NK    64
#define NS    48
#define MK    200   // knots per transform
#define GB    256   // lookup-grid buckets

__device__ __forceinline__ float rcp_fast(float x) { return __builtin_amdgcn_rcpf(x); }
__device__ __forceinline__ int imin(int a, int b) { return a < b ? a : b; }

// ---------------------------------------------------------------------------
// Kernel 1: 64 independent 48x48 QR factorizations (modified Gram-Schmidt).
// Row-major Qws[k][r][j] only (Qpack removed: core reads Q from LDS now).
// ---------------------------------------------------------------------------
__global__ __launch_bounds__(64) void qr_kernel(const float* __restrict__ Araw,
                                                float* __restrict__ Qws) {
  const int k = blockIdx.x;
  const int lane = threadIdx.x;
  const float* Ak = Araw + k * NS * NS;
  float col[NS];
#pragma unroll
  for (int r = 0; r < NS; ++r)
    col[r] = (lane < NS) ? Ak[r * NS + lane] : 0.f;

  for (int j = 0; j < NS; ++j) {
    float q[NS];
#pragma unroll
    for (int r = 0; r < NS; ++r)
      q[r] = __int_as_float(__builtin_amdgcn_readlane(__float_as_int(col[r]), j));
    float n0 = 0.f, n1 = 0.f, n2 = 0.f, n3 = 0.f;
#pragma unroll
    for (int r = 0; r < NS; r += 4) {
      n0 = fmaf(q[r+0], q[r+0], n0); n1 = fmaf(q[r+1], q[r+1], n1);
      n2 = fmaf(q[r+2], q[r+2], n2); n3 = fmaf(q[r+3], q[r+3], n3);
    }
    float rinv = 1.0f / sqrtf((n0 + n1) + (n2 + n3));
#pragma unroll
    for (int r = 0; r < NS; ++r) q[r] *= rinv;
    if (lane == j) {
#pragma unroll
      for (int r = 0; r < NS; ++r) col[r] = q[r];
    } else if (lane > j && lane < NS) {
      float d0 = 0.f, d1 = 0.f, d2 = 0.f, d3 = 0.f;
#pragma unroll
      for (int r = 0; r < NS; r += 4) {
        d0 = fmaf(q[r+0], col[r+0], d0); d1 = fmaf(q[r+1], col[r+1], d1);
        d2 = fmaf(q[r+2], col[r+2], d2); d3 = fmaf(q[r+3], col[r+3], d3);
      }
      float dt = (d0 + d1) + (d2 + d3);
#pragma unroll
      for (int r = 0; r < NS; ++r) col[r] = fmaf(-dt, q[r], col[r]);
    }
  }
  if (lane < NS) {
    float* Qk = Qws + k * NS * NS;
#pragma unroll
    for (int r = 0; r < NS; ++r) Qk[r * NS + lane] = col[r];
  }
}

// ---------------------------------------------------------------------------
// Kernel 2: knot tables. One wave per transform row t.
//  xxg[t][0..199]    knot x positions
//  ydk8[t][kk]       2x float4: (xK, 1/dx, yK, dy), (s, dK, dK1, dK+dK1-2s)
//  edge[t*2+{0,1}]   (xx0,yy0,del0,scale), (xxM,yyM,delM,0)
//  gridb[t][g] u8    start interval for bucket g
// ---------------------------------------------------------------------------
__global__ __launch_bounds__(256) void knots_kernel(
    const float* __restrict__ x0, const float* __restrict__ logdx,
    const float* __restrict__ y0, const float* __restrict__ logdy,
    const float* __restrict__ logderiv,
    float* __restrict__ xxg, float4* __restrict__ ydk8,
    float4* __restrict__ edge, unsigned char* __restrict__ gridb) {
  const int wid = threadIdx.x >> 6, lane = threadIdx.x & 63;
  const int t = blockIdx.x * 4 + wid;
  __shared__ float sxx[4][MK], syy[4][MK], sdel[4][MK];

  {
    const float* row = logdx + t * (MK - 1);
    int i0 = lane * 4;
    float e0 = (i0 + 0 < MK - 1) ? __expf(row[i0 + 0]) : 0.f;
    float e1 = (i0 + 1 < MK - 1) ? __expf(row[i0 + 1]) : 0.f;
    float e2 = (i0 + 2 < MK - 1) ? __expf(row[i0 + 2]) : 0.f;
    float e3 = (i0 + 3 < MK - 1) ? __expf(row[i0 + 3]) : 0.f;
    float p0 = e0, p1 = p0 + e1, p2 = p1 + e2, p3 = p2 + e3;
    float incl = p3;
#pragma unroll
    for (int off = 1; off < 64; off <<= 1) {
      float u = __shfl_up(incl, off, 64);
      if (lane >= off) incl += u;
    }
    float xv = x0[t];
    float base = xv + (incl - p3);
    float* xrow = xxg + t * MK;
    if (lane == 0) { xrow[0] = xv; sxx[wid][0] = xv; }
    if (i0 + 0 < MK - 1) { xrow[1+i0+0] = base + p0; sxx[wid][1+i0+0] = base + p0; }
    if (i0 + 1 < MK - 1) { xrow[1+i0+1] = base + p1; sxx[wid][1+i0+1] = base + p1; }
    if (i0 + 2 < MK - 1) { xrow[1+i0+2] = base + p2; sxx[wid][1+i0+2] = base + p2; }
    if (i0 + 3 < MK - 1) { xrow[1+i0+3] = base + p3; sxx[wid][1+i0+3] = base + p3; }
  }
  {
    const float* row = logdy + t * (MK - 1);
    int i0 = lane * 4;
    float e0 = (i0 + 0 < MK - 1) ? __expf(row[i0 + 0]) : 0.f;
    float e1 = (i0 + 1 < MK - 1) ? __expf(row[i0 + 1]) : 0.f;
    float e2 = (i0 + 2 < MK - 1) ? __expf(row[i0 + 2]) : 0.f;
    float e3 = (i0 + 3 < MK - 1) ? __expf(row[i0 + 3]) : 0.f;
    float p0 = e0, p1 = p0 + e1, p2 = p1 + e2, p3 = p2 + e3;
    float incl = p3;
#pragma unroll
    for (int off = 1; off < 64; off <<= 1) {
      float u = __shfl_up(incl, off, 64);
      if (lane >= off) incl += u;
    }
    float yv = y0[t];
    float base = yv + (incl - p3);
    if (lane == 0) syy[wid][0] = yv;
    if (i0 + 0 < MK - 1) syy[wid][1+i0+0] = base + p0;
    if (i0 + 1 < MK - 1) syy[wid][1+i0+1] = base + p1;
    if (i0 + 2 < MK - 1) syy[wid][1+i0+2] = base + p2;
    if (i0 + 3 < MK - 1) syy[wid][1+i0+3] = base + p3;
  }
  {
    const float* ld = logderiv + t * MK;
#pragma unroll
    for (int rep = 0; rep < 4; ++rep) {
      int m = lane + rep * 64;
      if (m < MK) sdel[wid][m] = __expf(ld[m]);
    }
  }
  __syncthreads();

#pragma unroll
  for (int rep = 0; rep < 4; ++rep) {
    int kk = lane + rep * 64;
    if (kk < MK - 1) {
      float xK = sxx[wid][kk], dx = sxx[wid][kk+1] - xK;
      float yK = syy[wid][kk], dy = syy[wid][kk+1] - yK;
      float rdx = 1.0f / dx;
      float s_ = dy * rdx;
      float dK = sdel[wid][kk], dK1 = sdel[wid][kk+1];
      ydk8[(t * (MK-1) + kk) * 2 + 0] = make_float4(xK, rdx, yK, dy);
      ydk8[(t * (MK-1) + kk) * 2 + 1] = make_float4(s_, dK, dK1, dK + dK1 - 2.f * s_);
    }
  }
  float xx0v = sxx[wid][0], xxMv = sxx[wid][MK-1];
  if (lane == 0) {
    float scale = (float)GB / (xxMv - xx0v);
    edge[t*2+0] = make_float4(xx0v, syy[wid][0],    sdel[wid][0],    scale);
    edge[t*2+1] = make_float4(xxMv, syy[wid][MK-1], sdel[wid][MK-1], 0.f);
  }
  float bw = (xxMv - xx0v) * (1.f / (float)GB);
#pragma unroll
  for (int i = 0; i < 4; ++i) {
    int g = lane * 4 + i;
    float L = xx0v + (float)g * bw;
    int p = 0;
#pragma unroll
    for (int st = 128; st >= 1; st >>= 1) {
      int cand = p + st;
      if (cand < MK && sxx[wid][cand] < L) p = cand;
    }
    gridb[t * GB + g] = (unsigned char)(p > MK-2 ? MK-2 : p);
  }
}

// ---------------------------------------------------------------------------
// Fused core (round 7): block = 256 thr = 4 waves, slice == wave-id, 64
// samples/block, nh-grouped XCD decode.
//
// Q IN LDS: round 6 showed VALUBusy 29.5% / occupancy 45% with per-thread
// wave-uniform Q loads from global. Those either scalarize to s_load (SMEM
// completes OUT-OF-ORDER on lgkmcnt, and the xs ds_reads share lgkmcnt, so
// interleaving forces lgkmcnt(0) drains each iteration) or stay as 288
// VMEM broadcasts/wave. Either way phases A/C alternate short FMA bursts
// with full waits. Fix: stage Qws[k] (9216 B) into LDS once per block;
// A/C inner loops become pure-DS (ds_read broadcast, conflict-free, DS is
// IN-ORDER on lgkmcnt -> counted waits pipeline). No SMEM/VMEM in A/C.
// LDS 23 KB -> 7 blocks/CU cap (VGPR cap 8 at 64 VGPR).
// ---------------------------------------------------------------------------
__global__ __launch_bounds__(256, 4) void core_fused(
    const float* __restrict__ data, const float* __restrict__ Qws,
    const float* __restrict__ xxg, const unsigned char* __restrict__ gridb,
    const float4* __restrict__ edge, const float4* __restrict__ ydk8,
    float* __restrict__ partial, float* __restrict__ out) {
  const int w = blockIdx.x;
  const int nh = w & 7, nw = (w >> 3) & 7, tile = w >> 6;   // nh-grouped decode
  const int k = nh * 8 + nw;
  const int n0 = tile * 64;
  const int tid = threadIdx.x;
  const int srel = tid & 63;                                    // sample 0..63
  const int slice = __builtin_amdgcn_readfirstlane(tid >> 6);   // 0..3 == kh

  __shared__ float qs[NS * NS];   // Q[k], row-major 48x48 (9216 B)
  __shared__ float xs[64][50];    // x, then reused for e (stride 50: 8B align)
  __shared__ float lp[4][64];     // per-slice logsum partials

  const int r_img = (4 * nh + slice + 2) & 31;   // circular shift rows
  const int c0 = 12 * nw + 6;                    // circular shift cols (wraps)

  // ---- stage Q into LDS (coalesced float4; Q is L2-resident) ----
  {
    const float4* Qg = (const float4*)(Qws + k * NS * NS);
    float4* q4 = (float4*)qs;
#pragma unroll
    for (int it = 0; it < 3; ++it) {
      int i = tid + it * 256;
      if (i < NS * NS / 4) q4[i] = Qg[i];
    }
  }

  // ---- stage x: read own 12-float chunk (sample srel, patch-row slice) ----
  float xreg[12];
  {
    const float* drow = data + (size_t)(n0 + srel) * NDIM + r_img * 96;
#pragma unroll
    for (int e = 0; e < 6; ++e) {
      int col = c0 + 2 * e; col -= (col >= 96) ? 96 : 0;
      float2 v = *(const float2*)(drow + col);
      xreg[2*e] = v.x; xreg[2*e+1] = v.y;
      *(float2*)&xs[srel][slice * 12 + 2*e] = v;
    }
  }
  __syncthreads();

  // ---- phase A: acc[12] = x . Q[:, slice*12 .. +11]  (pure LDS) ----
  float acc[12];
#pragma unroll
  for (int j = 0; j < 12; ++j) acc[j] = 0.f;
  {
    const float4* q4 = (const float4*)qs + slice * 3;   // + d*12 per row
#pragma unroll 4
    for (int d2 = 0; d2 < 24; ++d2) {              // d = 2*d2, 2*d2+1
      float2 xv = *(const float2*)&xs[srel][2 * d2];
      float4 a0 = q4[(2*d2)*12+0], a1 = q4[(2*d2)*12+1], a2 = q4[(2*d2)*12+2];
      float4 b0 = q4[(2*d2)*12+12], b1 = q4[(2*d2)*12+13], b2 = q4[(2*d2)*12+14];
      acc[0] = fmaf(xv.x, a0.x, acc[0]); acc[1] = fmaf(xv.x, a0.y, acc[1]);
      acc[2] = fmaf(xv.x, a0.z, acc[2]); acc[3] = fmaf(xv.x, a0.w, acc[3]);
      acc[4] = fmaf(xv.x, a1.x, acc[4]); acc[5] = fmaf(xv.x, a1.y, acc[5]);
      acc[6] = fmaf(xv.x, a1.z, acc[6]); acc[7] = fmaf(xv.x, a1.w, acc[7]);
      acc[8] = fmaf(xv.x, a2.x, acc[8]); acc[9] = fmaf(xv.x, a2.y, acc[9]);
      acc[10]= fmaf(xv.x, a2.z, acc[10]); acc[11]= fmaf(xv.x, a2.w, acc[11]);
      acc[0] = fmaf(xv.y, b0.x, acc[0]); acc[1] = fmaf(xv.y, b0.y, acc[1]);
      acc[2] = fmaf(xv.y, b0.z, acc[2]); acc[3] = fmaf(xv.y, b0.w, acc[3]);
      acc[4] = fmaf(xv.y, b1.x, acc[4]); acc[5] = fmaf(xv.y, b1.y, acc[5]);
      acc[6] = fmaf(xv.y, b1.z, acc[6]); acc[7] = fmaf(xv.y, b1.w, acc[7]);
      acc[8] = fmaf(xv.y, b2.x, acc[8]); acc[9] = fmaf(xv.y, b2.y, acc[9]);
      acc[10]= fmaf(xv.y, b2.z, acc[10]); acc[11]= fmaf(xv.y, b2.w, acc[11]);
    }
  }

  // ---- phase B: spline on 12 values, e = y - d0 (registers only) ----
  // log-sum as product-of-12 then one log: dd ~ O(1), product in fp32 range.
  float prod = 1.f;
  {
    const unsigned char* gk = gridb + (size_t)k * NS * GB;
    const float4* yk = ydk8 + (size_t)k * NS * (MK - 1) * 2;
    const float4* ek = edge + (size_t)k * NS * 2;
    const float* xk = xxg + (size_t)k * NS * MK;
#pragma unroll
    for (int jj = 0; jj < 12; ++jj) {
      const int jg = slice * 12 + jj;
      float v = acc[jj];
      float4 e0 = ek[2*jg], e1 = ek[2*jg+1];
      int g = (int)((v - e0.x) * e0.w);
      g = g < 0 ? 0 : (g > GB-1 ? GB-1 : g);
      int kk = gk[jg * GB + g];
      const float* xr = xk + jg * MK;
      // parallel refine: monotone xx => independent compares sum correctly
      float xA = xr[imin(kk + 1, MK - 1)];
      float xB = xr[imin(kk + 2, MK - 1)];
      float xC = xr[imin(kk + 3, MK - 1)];
      kk += (int)(kk + 1 <= MK-2 && xA < v) + (int)(kk + 2 <= MK-2 && xB < v)
          + (int)(kk + 3 <= MK-2 && xC < v);
      float4 r0 = yk[(jg * (MK-1) + kk) * 2 + 0];   // (xK, rdx, yK, dy)
      float4 r1 = yk[(jg * (MK-1) + kk) * 2 + 1];   // (s, dK, dK1, d2s)
      float xi = (v - r0.x) * r0.y;
      xi = fminf(fmaxf(xi, 0.f), 1.f);
      float omxi = 1.f - xi, xi1 = xi * omxi, xi2 = xi * xi;
      float denom = fmaf(r1.w, xi1, r1.x);
      float rden = rcp_fast(denom);
      float y_in = fmaf(r0.w * fmaf(r1.x, xi2, r1.y * xi1), rden, r0.z);
      float d_in = r1.x * r1.x * (r1.z * xi2 + 2.f * r1.x * xi1 + r1.y * omxi * omxi) * (rden * rden);
      bool below = v <= e0.x, above = v > e1.x;
      float yv = below ? fmaf(e0.z, v - e0.x, e0.y)
               : (above ? fmaf(e1.z, v - e1.x, e1.y) : y_in);
      float dd = below ? e0.z : (above ? e1.z : d_in);
      prod *= dd;
      acc[jj] = yv - v;
    }
  }

  // ---- publish e into xs (reuse; x stays in xreg) + logsum partial ----
  __syncthreads();   // all phase-A reads of xs complete
#pragma unroll
  for (int jj = 0; jj < 12; jj += 2)
    *(float2*)&xs[srel][slice * 12 + jj] = make_float2(acc[jj], acc[jj+1]);
  lp[slice][srel] = __logf(prod);
  __syncthreads();

  // ---- phase C: r[dd] = e . Q[slice*12+dd][:]  (pure LDS) ----
  float r[12];
#pragma unroll
  for (int d = 0; d < 12; ++d) r[d] = 0.f;
  {
    const float* qc = qs + (slice * 12) * NS;
#pragma unroll
    for (int jc = 0; jc < 12; ++jc) {
      float2 eab = *(const float2*)&xs[srel][4 * jc];
      float2 ecd = *(const float2*)&xs[srel][4 * jc + 2];
#pragma unroll
      for (int dd = 0; dd < 12; ++dd) {
        float4 q = *(const float4*)(qc + dd * NS + 4 * jc);
        r[dd] = fmaf(ecd.y, q.w, fmaf(ecd.x, q.z, fmaf(eab.y, q.y, fmaf(eab.x, q.x, r[dd]))));
      }
    }
  }

  // ---- epilogue: out = x + r, same chunk this thread loaded ----
  {
    float* orow = out + (size_t)(n0 + srel) * NDIM + r_img * 96;
#pragma unroll
    for (int e = 0; e < 6; ++e) {
      int col = c0 + 2 * e; col -= (col >= 96) ? 96 : 0;
      *(float2*)(orow + col) = make_float2(xreg[2*e] + r[2*e],
                                           xreg[2*e+1] + r[2*e+1]);
    }
  }

  // ---- logsum reduction across slices (global store last) ----
  if (tid < 64) {
    float t = lp[0][tid] + lp[1][tid] + lp[2][tid] + lp[3][tid];
    partial[(size_t)k * NSMP + n0 + tid] = t;
  }
}

__global__ __launch_bounds__(256) void reduce_kernel(const float* __restrict__ partial,
                                                     float* __restrict__ logj) {
  int n = blockIdx.x * 256 + threadIdx.x;
  float s = 0.f;
#pragma unroll
  for (int k = 0; k < NK; ++k) s += partial[k * NSMP + n];
  logj[n] = s;
}

extern "C" void kernel_launch(void* const* d_in, const int* in_sizes, int n_in,
                              void* d_out, int out_size, void* d_ws, size_t ws_size,
                              hipStream_t stream) {
  const float* data     = (const float*)d_in[0];
  const float* Araw     = (const float*)d_in[1];
  const float* x0       = (const float*)d_in[2];
  const float* logdx    = (const float*)d_in[3];
  const float* y0       = (const float*)d_in[4];
  const float* logdy    = (const float*)d_in[5];
  const float* logderiv = (const float*)d_in[6];
  float* out = (float*)d_out;
  float* ws  = (float*)d_ws;

  float*         Qws   = ws;                                 // 589,824 B
  float*         xxg   = Qws + 64 * NS * NS;                 // 2,457,600 B
  float4*        ydk8  = (float4*)(xxg + 3072 * MK);         // 19,562,496 B
  float4*        edge  = ydk8 + 3072 * (MK - 1) * 2;         // 98,304 B
  unsigned char* gridb = (unsigned char*)(edge + 3072 * 2);  // 786,432 B
  float*         partial = (float*)(gridb + 3072 * GB);      // 2,097,152 B

  qr_kernel<<<64, 64, 0, stream>>>(Araw, Qws);
  knots_kernel<<<768, 256, 0, stream>>>(x0, logdx, y0, logdy, logderiv,
                                        xxg, ydk8, edge, gridb);
  core_fused<<<(NSMP / 64) * 64, 256, 0, stream>>>(data, Qws, xxg,
                                                   gridb, edge, ydk8,
                                                   partial, out);
  reduce_kernel<<<32, 256, 0, stream>>>(partial, out + (size_t)NSMP * NDIM);
}